// Round 1
// baseline (225.619 us; speedup 1.0000x reference)
//
#include <hip/hip_runtime.h>
#include <hip/hip_bf16.h>

// out[b,n,o] = relu( sum_m efm[b,n,m] * z[b,m,o] + bias[o] )
// where z[b,m,o] = sum_d nfm[b,m,d] * W[o,d]   (associativity of matmul)
//
// B=512, N=256, D=50 (padded to 64). One block per batch, 8 waves, MFMA bf16.

typedef float f32x4 __attribute__((ext_vector_type(4)));
typedef short s16x8 __attribute__((ext_vector_type(8)));

#define TPB 512

__device__ __forceinline__ unsigned short f2bf(float f) {
    union { float f; unsigned u; } a; a.f = f;
    unsigned u = a.u;
    unsigned rounded = u + 0x7fffu + ((u >> 16) & 1u);   // RNE to bf16
    return (unsigned short)(rounded >> 16);
}

__global__ __launch_bounds__(TPB, 4)
void gconv_fused(const float* __restrict__ nfm,
                 const float* __restrict__ efm,
                 const float* __restrict__ W,
                 const float* __restrict__ bias,
                 float* __restrict__ out)
{
    // nfm_s: [256 rows][72 pad] bf16 (valid k<50, zero-padded to 64)
    // w_s  : [64 o][72 pad] bf16 (valid o<50,k<50, zero-padded)
    // z_s  : transposed z: [64 o][264 pad] bf16 over m=0..255
    __shared__ unsigned short nfm_s[256 * 72];
    __shared__ unsigned short w_s[64 * 72];
    __shared__ unsigned short z_s[64 * 264];

    const int tid   = threadIdx.x;
    const int lane  = tid & 63;
    const int wv    = tid >> 6;        // wave 0..7
    const int col16 = lane & 15;
    const int kg    = lane >> 4;       // 0..3
    const int kg8   = kg * 8;
    const int b     = blockIdx.x;

    const float* nfm_b = nfm + (size_t)b * (256 * 50);
    const float* efm_b = efm + (size_t)b * (256 * 256);
    float*       out_b = out + (size_t)b * (256 * 50);

    // ---- zero LDS pads (whole buffers; valid parts overwritten below) ----
    {
        unsigned* p = (unsigned*)nfm_s;
        for (int i = tid; i < 256 * 72 / 2; i += TPB) p[i] = 0u;
        unsigned* q = (unsigned*)w_s;
        for (int i = tid; i < 64 * 72 / 2; i += TPB) q[i] = 0u;
    }
    __syncthreads();

    // ---- stage nfm[b] and W as bf16 into LDS ----
    for (int i = tid; i < 3200; i += TPB) {            // 12800 f32 / 4
        f32x4 v = *(const f32x4*)(nfm_b + i * 4);
        int e = i * 4;
        #pragma unroll
        for (int j = 0; j < 4; ++j) {
            int r = (e + j) / 50, k = (e + j) % 50;
            nfm_s[r * 72 + k] = f2bf(v[j]);
        }
    }
    for (int i = tid; i < 625; i += TPB) {             // 2500 f32 / 4
        f32x4 v = *(const f32x4*)(W + i * 4);
        int e = i * 4;
        #pragma unroll
        for (int j = 0; j < 4; ++j) {
            int o = (e + j) / 50, k = (e + j) % 50;
            w_s[o * 72 + k] = f2bf(v[j]);
        }
    }

    // bias per lane per o-tile
    float bia[4];
    #pragma unroll
    for (int ot = 0; ot < 4; ++ot) {
        int c = ot * 16 + col16;
        bia[ot] = (c < 50) ? bias[c] : 0.f;
    }
    __syncthreads();

    // ---- phase 1: z = nfm @ W^T, each wave does 32 rows of m ----
    {
        s16x8 wf[2][4];   // B-frags: B[k][o] = W[o][k], contiguous along k
        #pragma unroll
        for (int kk = 0; kk < 2; ++kk)
            #pragma unroll
            for (int ot = 0; ot < 4; ++ot)
                wf[kk][ot] = *(const s16x8*)&w_s[(ot * 16 + col16) * 72 + kk * 32 + kg8];

        #pragma unroll
        for (int mt = 0; mt < 2; ++mt) {
            int row = wv * 32 + mt * 16 + col16;
            s16x8 a0 = *(const s16x8*)&nfm_s[row * 72 + kg8];
            s16x8 a1 = *(const s16x8*)&nfm_s[row * 72 + 32 + kg8];
            #pragma unroll
            for (int ot = 0; ot < 4; ++ot) {
                f32x4 acc = {0.f, 0.f, 0.f, 0.f};
                acc = __builtin_amdgcn_mfma_f32_16x16x32_bf16(a0, wf[0][ot], acc, 0, 0, 0);
                acc = __builtin_amdgcn_mfma_f32_16x16x32_bf16(a1, wf[1][ot], acc, 0, 0, 0);
                // C/D layout: col = lane&15, row = (lane>>4)*4 + r  (m89-verified)
                #pragma unroll
                for (int r = 0; r < 4; ++r) {
                    int m = wv * 32 + mt * 16 + kg * 4 + r;
                    int o = ot * 16 + col16;
                    z_s[o * 264 + m] = f2bf(acc[r]);   // store transposed
                }
            }
        }
    }
    __syncthreads();

    // ---- phase 2: out = relu(efm @ z + bias); wave owns 32 output rows ----
    f32x4 acc[2][4];
    #pragma unroll
    for (int mt = 0; mt < 2; ++mt)
        #pragma unroll
        for (int ot = 0; ot < 4; ++ot)
            acc[mt][ot] = (f32x4){0.f, 0.f, 0.f, 0.f};

    const int wrow = wv * 32;
    #pragma unroll
    for (int ks = 0; ks < 8; ++ks) {                  // K = 256, 32 per step
        s16x8 bf[4];                                  // z_s[o][m..m+7] contiguous
        #pragma unroll
        for (int ot = 0; ot < 4; ++ot)
            bf[ot] = *(const s16x8*)&z_s[(ot * 16 + col16) * 264 + ks * 32 + kg8];
        #pragma unroll
        for (int mt = 0; mt < 2; ++mt) {
            const float* ap = efm_b + (wrow + mt * 16 + col16) * 256 + ks * 32 + kg8;
            f32x4 lo = *(const f32x4*)ap;
            f32x4 hi = *(const f32x4*)(ap + 4);
            s16x8 af;
            #pragma unroll
            for (int j = 0; j < 4; ++j) {
                af[j]     = (short)f2bf(lo[j]);
                af[4 + j] = (short)f2bf(hi[j]);
            }
            #pragma unroll
            for (int ot = 0; ot < 4; ++ot)
                acc[mt][ot] = __builtin_amdgcn_mfma_f32_16x16x32_bf16(af, bf[ot], acc[mt][ot], 0, 0, 0);
        }
    }

    // ---- epilogue: bias + relu + masked store (o < 50) ----
    #pragma unroll
    for (int mt = 0; mt < 2; ++mt)
        #pragma unroll
        for (int ot = 0; ot < 4; ++ot) {
            int o = ot * 16 + col16;
            if (o < 50) {
                #pragma unroll
                for (int r = 0; r < 4; ++r) {
                    int n = wrow + mt * 16 + kg * 4 + r;
                    out_b[n * 50 + o] = fmaxf(acc[mt][ot][r] + bia[ot], 0.f);
                }
            }
        }
}

extern "C" void kernel_launch(void* const* d_in, const int* in_sizes, int n_in,
                              void* d_out, int out_size, void* d_ws, size_t ws_size,
                              hipStream_t stream) {
    const float* nfm  = (const float*)d_in[0];   // [512,256,50]
    const float* efm  = (const float*)d_in[1];   // [512,256,256]
    const float* W    = (const float*)d_in[2];   // [50,50]
    const float* bias = (const float*)d_in[3];   // [50]
    float* out = (float*)d_out;                  // [512,256,50]

    gconv_fused<<<dim3(512), dim3(TPB), 0, stream>>>(nfm, efm, W, bias, out);
}